// Round 9
// baseline (401.502 us; speedup 1.0000x reference)
//
#include <hip/hip_runtime.h>
#include <hip/hip_bf16.h>

typedef __hip_bfloat16 bf16;
typedef unsigned short u16;
typedef __attribute__((ext_vector_type(8))) short bfrag;   // 8 bf16 = 4 VGPR
typedef __attribute__((ext_vector_type(4))) float cfrag;   // 4 f32 acc

union BF { bfrag v; u16 u[8]; unsigned w[4]; };
union CF { cfrag v; float f[4]; };

#define MFMA(a,b,c) __builtin_amdgcn_mfma_f32_16x16x32_bf16(a,b,c,0,0,0)

#define BB   256
#define NN   128
#define IND  9
#define HDD  128
#define LLY  4
#define OUTD 60
#define LOG2E 1.44269504f
#define STR  136                                  // u16 LDS row stride

__device__ __forceinline__ float b2f(bf16 v){ return __bfloat162float(v); }
__device__ __forceinline__ float u2f(u16 u){ return __uint_as_float(((unsigned)u) << 16); }
__device__ __forceinline__ u16 f2bf_bits(float f){
    unsigned u = __float_as_uint(f);
    return (u16)((u + 0x7FFFu + ((u >> 16) & 1u)) >> 16);   // RNE
}
__device__ __forceinline__ unsigned pk2(float a, float b){
    union { __hip_bfloat162 h; unsigned u; } c;
    c.h = __float22bfloat162_rn(make_float2(a, b));          // v_cvt_pk_bf16_f32
    return c.u;
}
__device__ __forceinline__ float wave_sum(float v){
    #pragma unroll
    for (int m = 32; m; m >>= 1) v += __shfl_xor(v, m, 64);
    return v;
}
__device__ __forceinline__ float ldin(const void* p, int i, bool isbf){
    return isbf ? b2f(((const bf16*)p)[i]) : ((const float*)p)[i];
}

struct SrcPtrs { const void* p[28]; };

// compact f32 params: cw0 cb1152 bg1280 bb1408 bm1536 bv1664 lng1792 lnb2304
// fb1:2816 fb2:3840 ng4352 nb4480 pw4608 pb20992 hw1:21120 hb1:29312 hw2:29376 hb2:33216
__device__ const int NCV_OFF[19] = {0,1152,1280,1408,1536,1664,1792,2304,2816,3840,
                                    4352,4480,4608,20992,21120,29312,29376,33216,33276};
__device__ const int NCV_SRC[18] = {1,2,3,4,5,6,10,11,13,15,16,17,18,19,20,21,22,23};

// ====== prep: detect + convert + LDS-tiled weight transposes + WAb + ew2 + Aw ======
// blocks: [0,131) cvt | [131,147) WT | [147,179) w1T | [179,211) w2T
//         [211,243) WAb | [243,307) ew2 | [307,435) Aw
__global__ __launch_bounds__(256) void k_prep(
    SrcPtrs S, float* __restrict__ pf,
    u16* __restrict__ WT, u16* __restrict__ w1T, u16* __restrict__ w2T,
    u16* __restrict__ WAb, u16* __restrict__ ew2, u16* __restrict__ Aw16,
    int* __restrict__ flagOut)
{
    __shared__ float tile[64][65];
    const unsigned* xw = (const unsigned*)S.p[0];
    int lane = threadIdx.x & 63;
    int cnt = 0;
    for (int i = lane; i < 512; i += 64) {
        float v = __uint_as_float((xw[i] & 0xFFFFu) << 16);
        if (!(fabsf(v) < 32.f)) cnt++;
    }
    bool isbf = wave_sum((float)cnt) < 16.f;
    if (blockIdx.x == 0 && threadIdx.x == 0) *flagOut = isbf ? 1 : 0;

    int blk = blockIdx.x, tid = threadIdx.x;
    if (blk < 131) {                               // small-param f32 convert
        int idx = blk * 256 + tid;
        if (idx < 33276) {
            int y = 17;
            #pragma unroll 1
            for (int t = 1; t < 18; t++) if (idx < NCV_OFF[t]) { y = t - 1; break; }
            pf[idx] = ldin(S.p[NCV_SRC[y]], idx - NCV_OFF[y], isbf);
        }
    } else if (blk < 211) {                        // tiled transposes: src[K][N] -> dst[N][K] bf16
        const void* src; u16* dst; int K, N, k0, n0;
        if (blk < 147) {                           // WT: per l 128x128, 4 tiles
            int t = blk - 131, l = t >> 2, tt = t & 3;
            src = (const char*)S.p[7] + (size_t)l * 16384 * (isbf ? 2 : 4);
            dst = WT + l * 16384; K = 128; N = 128; k0 = (tt >> 1) * 64; n0 = (tt & 1) * 64;
        } else if (blk < 179) {                    // w1T: per l 128x256, 8 tiles
            int t = blk - 147, l = t >> 3, tt = t & 7;
            src = (const char*)S.p[12] + (size_t)l * 32768 * (isbf ? 2 : 4);
            dst = w1T + l * 32768; K = 128; N = 256; k0 = (tt >> 2) * 64; n0 = (tt & 3) * 64;
        } else {                                   // w2T: per l 256x128, 8 tiles
            int t = blk - 179, l = t >> 3, tt = t & 7;
            src = (const char*)S.p[14] + (size_t)l * 32768 * (isbf ? 2 : 4);
            dst = w2T + l * 32768; K = 256; N = 128; k0 = (tt & 3) * 64; n0 = (tt >> 2) * 64;
        }
        int ty = tid >> 6, tx = tid & 63;
        #pragma unroll 4
        for (int i = 0; i < 16; i++) {
            int row = ty * 16 + i;
            tile[row][tx] = ldin(src, (k0 + row) * N + n0 + tx, isbf);
        }
        __syncthreads();
        #pragma unroll 4
        for (int i = 0; i < 16; i++) {
            int row = ty * 16 + i;
            dst[(n0 + row) * K + k0 + tx] = f2bf_bits(tile[tx][row]);
        }
    } else if (blk < 243) {                        // WAb[l][n16][k128] = (W @ [asrc|adst])^T
        int j = (blk - 211) * 256 + tid;           // 8192
        int l = j >> 11, r = j & 2047, n = r >> 7, k = r & 127;
        int h = n & 7;
        const void* ap = (n < 8) ? S.p[8] : S.p[9];
        float sacc = 0.f;
        #pragma unroll 1
        for (int d = 0; d < 16; d++)
            sacc += ldin(S.p[7], l * 16384 + k * 128 + h * 16 + d, isbf)
                  * ldin(ap, l * 128 + h * 16 + d, isbf);
        WAb[j] = f2bf_bits(sacc);
    } else if (blk < 307) {                        // ew2 = log2e*(mask? ewa : -1e30)
        int j = (blk - 243) * 256 + tid;
        float sav = ldin(S.p[24], j, isbf);
        float ewv = ldin(S.p[27], j, isbf);
        ew2[j] = f2bf_bits(sav > 0.f ? ewv * LOG2E : -1e30f);
    } else {                                       // Aw row-normalized * 0.4, bf16
        __shared__ float red[2];
        int i = blk - 307, j = tid & 127;
        float v = 0.f;
        if (tid < 128) {
            float wmv = ldin(S.p[25], i * 128 + j, isbf);
            float wpv = ldin(S.p[26], i * 128 + j, isbf);
            v = wmv / (1.f + __expf(-wpv));
            float sm = wave_sum(v);
            if ((tid & 63) == 0) red[tid >> 6] = sm;
        }
        __syncthreads();
        if (tid < 128) {
            float tot = red[0] + red[1];
            Aw16[i * 128 + j] = f2bf_bits(0.4f * v / (tot + 1e-5f));
        }
    }
}

// ====== whole-network megakernel: 1 block/graph, 512 thr = 8 waves, 16 rows/wave ======
// LDS: U1 = h16 (P1 A-op) / gbuf (P4-5)  [128][STR] u16   (wave-private rows)
//      U2 = hpT (P1-P2', cross-wave) / hid (P5)  [128][STR] u16
//      hf32 = residual f32 [128][132]  (wave-private rows)
//      st2: s2 f32[0,1024) | t2u bf16 @f32-idx[1024,1536) | invb f32[1536,2560)
#define LDSB (128*STR*2*2 + 128*132*4 + 2560*4)
__global__ __launch_bounds__(512, 2) void k_net(
    const void* __restrict__ xraw, const int* __restrict__ flag,
    const float* __restrict__ pf,
    const u16* __restrict__ WTg, const u16* __restrict__ WAbg,
    const u16* __restrict__ Awg, const u16* __restrict__ ew2g,
    const u16* __restrict__ w1Tg, const u16* __restrict__ w2Tg,
    void* __restrict__ outv)
{
    extern __shared__ __align__(16) char smem[];
    u16* U1 = (u16*)smem;                      // [128][STR]
    u16* U2 = U1 + 128 * STR;                  // [128][STR]
    float* hf32 = (float*)(U2 + 128 * STR);    // [128][132]
    float* st2  = hf32 + 128 * 132;            // 2560 f32
    float* s2   = st2;                         // [8][128] f32
    u16*   t2u  = (u16*)(st2 + 1024);          // [8][128] bf16
    float* invb = st2 + 1536;                  // [8][128] f32

    const int b = blockIdx.x;
    const int tid = threadIdx.x, lane = tid & 63, wv = tid >> 6;
    const int l15 = lane & 15, kg = lane >> 4;
    const int wrow = wv * 16;
    const int arow = wrow + l15;               // this lane's A-frag row
    const bool isbf = (*flag != 0);

    // ---------- embed: conv1d + BN + relu -> hf32 + U1(bf16) ----------
    {
        float xr[4][IND];
        #pragma unroll
        for (int r = 0; r < 4; r++) {
            int bn = b * NN + wrow + kg * 4 + r;
            #pragma unroll
            for (int k = 0; k < IND; k++) xr[r][k] = ldin(xraw, bn * IND + k, isbf);
        }
        #pragma unroll 1
        for (int nt = 0; nt < 8; nt++) {
            int d = nt * 16 + l15;
            float cwreg[IND];
            #pragma unroll
            for (int k = 0; k < IND; k++) cwreg[k] = pf[d * IND + k];
            float scale = rsqrtf(pf[1664 + d] + 1e-5f) * pf[1280 + d];
            float bias  = pf[1408 + d] - pf[1536 + d] * scale;
            float cbd   = pf[1152 + d];
            #pragma unroll
            for (int r = 0; r < 4; r++) {
                float a = cbd;
                #pragma unroll
                for (int k = 0; k < IND; k++) a = fmaf(xr[r][k], cwreg[k], a);
                a = fmaxf(fmaf(a, scale, bias), 0.f);
                int row = wrow + kg * 4 + r;
                hf32[row * 132 + d] = a;
                U1[row * STR + d] = f2bf_bits(a);
            }
        }
    }

    // ---------- 4 layers ----------
    #pragma unroll 1
    for (int l = 0; l < LLY; l++) {
        const u16* WT  = WTg  + l * 16384;
        const u16* WAb = WAbg + l * 2048;
        const u16* w1T = w1Tg + l * 32768;
        const u16* w2T = w2Tg + l * 32768;
        const float* fb1 = pf + 2816 + l * 256;
        const float* fb2 = pf + 3840 + l * 128;
        const float* lng = pf + 1792 + l * 128;
        const float* lnb = pf + 2304 + l * 128;

        __syncthreads();                       // U2/s2/t2 free (prior cross-wave readers done)

        // P1: hp = h @ W (own rows -> hpT) + s,t = h @ (W·a)
        {
            CF acc[8], ast;
            #pragma unroll
            for (int r = 0; r < 4; r++) ast.f[r] = 0.f;
            #pragma unroll
            for (int nt = 0; nt < 8; nt++)
                #pragma unroll
                for (int r = 0; r < 4; r++) acc[nt].f[r] = 0.f;
            #pragma unroll
            for (int kk = 0; kk < 4; kk++) {
                bfrag af  = *(const bfrag*)&U1[arow * STR + kk*32 + kg*8];
                bfrag wab = *(const bfrag*)&WAb[l15 * 128 + kk*32 + kg*8];
                ast.v = MFMA(af, wab, ast.v);
                #pragma unroll
                for (int nt = 0; nt < 8; nt++) {
                    bfrag bw = *(const bfrag*)&WT[(nt*16 + l15) * 128 + kk*32 + kg*8];
                    acc[nt].v = MFMA(af, bw, acc[nt].v);
                }
            }
            #pragma unroll
            for (int nt = 0; nt < 8; nt++) {
                int col = nt*16 + l15;
                #pragma unroll
                for (int rp = 0; rp < 2; rp++) {
                    int row = wrow + kg*4 + rp*2;
                    *(unsigned*)&U2[col * STR + row] = pk2(acc[nt].f[rp*2], acc[nt].f[rp*2+1]);
                }
            }
            #pragma unroll
            for (int r = 0; r < 4; r++) {      // s (cols 0-7) f32, t (cols 8-15) bf16
                int node = wrow + kg*4 + r;
                float v = ast.f[r] * LOG2E;
                if (l15 < 8) s2[l15 * 128 + node] = v;
                else         t2u[(l15 - 8) * 128 + node] = f2bf_bits(v);
            }
        }
        __syncthreads();                       // hpT, s2, t2 ready

        // P2: strong attention, UNNORMALIZED P MFMA; 0.6*inv -> invb (own row)
        CF accS[8];
        #pragma unroll
        for (int nt = 0; nt < 8; nt++)
            #pragma unroll
            for (int r = 0; r < 4; r++) accS[nt].f[r] = 0.f;
        BF e2f[4];
        #pragma unroll
        for (int kk = 0; kk < 4; kk++)         // h-invariant edge bias, hoisted
            e2f[kk].v = *(const bfrag*)&ew2g[arow * 128 + kk*32 + kg*8];
        #pragma unroll 1
        for (int h = 0; h < 8; h++) {
            float sA = s2[h * 128 + arow];
            float sm = 0.f;
            #pragma unroll
            for (int kk = 0; kk < 4; kk++) {
                bfrag hb = *(const bfrag*)&U2[(h*16 + l15) * STR + kk*32 + kg*8];
                BF tb; tb.v = *(const bfrag*)&t2u[h * 128 + kk*32 + kg*8];
                BF pb;
                float p0[8];
                #pragma unroll
                for (int j = 0; j < 8; j++) {
                    float x2 = sA + u2f(tb.u[j]);
                    float lk = fmaxf(x2, 0.2f * x2);                  // log2e*leaky
                    float p = __builtin_amdgcn_exp2f(lk + u2f(e2f[kk].u[j]));
                    p0[j] = p; sm += p;
                }
                #pragma unroll
                for (int q = 0; q < 4; q++) pb.w[q] = pk2(p0[2*q], p0[2*q+1]);
                accS[h].v = MFMA(pb.v, hb, accS[h].v);                // no wait on sm chain
            }
            sm += __shfl_xor(sm, 16, 64);
            sm += __shfl_xor(sm, 32, 64);
            invb[h * 128 + arow] = 0.6f * __builtin_amdgcn_rcpf(sm);
        }
        // scale accS by 0.6*inv of each C-row (same wave's rows -> no barrier)
        #pragma unroll
        for (int h = 0; h < 8; h++) {
            const float4 iv = *(const float4*)&invb[h * 128 + wrow + kg*4];
            accS[h].f[0] *= iv.x; accS[h].f[1] *= iv.y;
            accS[h].f[2] *= iv.z; accS[h].f[3] *= iv.w;
        }

        // P3: weak accumulates into accS (Aw pre-scaled by 0.4)
        #pragma unroll
        for (int kk = 0; kk < 4; kk++) {
            bfrag awf = *(const bfrag*)&Awg[arow * 128 + kk*32 + kg*8];
            #pragma unroll
            for (int nt = 0; nt < 8; nt++) {
                bfrag hb2 = *(const bfrag*)&U2[(nt*16 + l15) * STR + kk*32 + kg*8];
                accS[nt].v = MFMA(awf, hb2, accS[nt].v);
            }
        }

        // P4: g = relu(acc), LN -> gbuf (U1, own rows; U1's h16 dead after P1)
        #pragma unroll
        for (int r = 0; r < 4; r++) {
            float s1 = 0.f, sq = 0.f;
            #pragma unroll
            for (int nt = 0; nt < 8; nt++) {
                float x = fmaxf(accS[nt].f[r], 0.f);
                accS[nt].f[r] = x; s1 += x; sq = fmaf(x, x, sq);
            }
            #pragma unroll
            for (int m = 1; m <= 8; m <<= 1) { s1 += __shfl_xor(s1, m, 64); sq += __shfl_xor(sq, m, 64); }
            float mu = s1 * (1.f / 128.f);
            float var = sq * (1.f / 128.f) - mu * mu;
            float rs = rsqrtf(fmaxf(var, 0.f) + 1e-5f);
            #pragma unroll
            for (int nt = 0; nt < 8; nt++) {
                int col = nt*16 + l15;
                U1[(wrow + kg*4 + r) * STR + col] =
                    f2bf_bits(fmaf((accS[nt].f[r] - mu) * rs, lng[col], lnb[col]));
            }
        }

        // P5: FFN (own rows); hid in U2 (hpT reads done after P3... cross-wave reads of
        // hpT end at P3; our own wave passed P3, but other waves may lag -> they only read
        // hpT cols (nt*16+l15) x all rows; we overwrite U2 rows... needs all waves past P3.
        __syncthreads();                       // everyone past P3 (last cross-wave hpT read)
        CF acc2[8];
        #pragma unroll
        for (int nt = 0; nt < 8; nt++)
            #pragma unroll
            for (int r = 0; r < 4; r++) acc2[nt].f[r] = 0.f;
        #pragma unroll 1
        for (int nh = 0; nh < 2; nh++) {
            CF a1[8];
            #pragma unroll
            for (int nt = 0; nt < 8; nt++)
                #pragma unroll
                for (int r = 0; r < 4; r++) a1[nt].f[r] = 0.f;
            #pragma unroll
            for (int kk = 0; kk < 4; kk++) {
                bfrag gf = *(const bfrag*)&U1[arow * STR + kk*32 + kg*8];
                #pragma unroll
                for (int nt = 0; nt < 8; nt++) {
                    bfrag wf = *(const bfrag*)&w1T[(nh*128 + nt*16 + l15) * 128 + kk*32 + kg*8];
                    a1[nt].v = MFMA(gf, wf, a1[nt].v);
                }
            }
            #pragma unroll
            for (int nt = 0; nt < 8; nt++) {
                int col = nt*16 + l15;
                float b1v = fb1[nh*128 + col];
                #pragma unroll
                for (int r = 0; r < 4; r++)
                    U2[(wrow + kg*4 + r) * STR + col] = f2bf_bits(fmaxf(a1[nt].f[r] + b1v, 0.f));
            }
            #pragma unroll
            for (int kk = 0; kk < 4; kk++) {
                bfrag hf = *(const bfrag*)&U2[arow * STR + kk*32 + kg*8];
                #pragma unroll
                for (int nt = 0; nt < 8; nt++) {
                    bfrag wf = *(const bfrag*)&w2T[(nt*16 + l15) * 256 + nh*128 + kk*32 + kg*8];
                    acc2[nt].v = MFMA(hf, wf, acc2[nt].v);
                }
            }
        }

        // epilogue: h += ffn + b2 (hf32, own rows); rebuild U1 bf16 for next layer
        #pragma unroll
        for (int nt = 0; nt < 8; nt++) {
            int col = nt*16 + l15;
            float b2v = fb2[col];
            #pragma unroll
            for (int r = 0; r < 4; r++) {
                int row = wrow + kg*4 + r;
                float hv = hf32[row * 132 + col] + acc2[nt].f[r] + b2v;
                hf32[row * 132 + col] = hv;
                if (l < LLY - 1) U1[row * STR + col] = f2bf_bits(hv);
            }
        }
    }

    // ---------- final LN + node-sum (proj commutes with mean) + head ----------
    const float* ng = pf + 4352;
    const float* nb = pf + 4480;
    float pacc[8];
    #pragma unroll
    for (int nt = 0; nt < 8; nt++) pacc[nt] = 0.f;
    #pragma unroll
    for (int r = 0; r < 4; r++) {
        int row = wrow + kg*4 + r;
        float hvv[8];
        float s1 = 0.f, sq = 0.f;
        #pragma unroll
        for (int nt = 0; nt < 8; nt++) {
            float x = hf32[row * 132 + nt*16 + l15];
            hvv[nt] = x; s1 += x; sq = fmaf(x, x, sq);
        }
        #pragma unroll
        for (int m = 1; m <= 8; m <<= 1) { s1 += __shfl_xor(s1, m, 64); sq += __shfl_xor(sq, m, 64); }
        float mu = s1 * (1.f / 128.f);
        float var = sq * (1.f / 128.f) - mu * mu;
        float rs = rsqrtf(fmaxf(var, 0.f) + 1e-5f);
        #pragma unroll
        for (int nt = 0; nt < 8; nt++)
            pacc[nt] += fmaf((hvv[nt] - mu) * rs, ng[nt*16 + l15], nb[nt*16 + l15]);
    }
    #pragma unroll
    for (int nt = 0; nt < 8; nt++) {
        pacc[nt] += __shfl_xor(pacc[nt], 16, 64);
        pacc[nt] += __shfl_xor(pacc[nt], 32, 64);
    }
    __syncthreads();                           // s2/t2/invb dead everywhere -> reuse st2
    if (kg == 0) {
        #pragma unroll
        for (int nt = 0; nt < 8; nt++) st2[wv * 128 + nt*16 + l15] = pacc[nt];
    }
    __syncthreads();
    if (tid < 128) {                           // pooled mean
        float tot = 0.f;
        #pragma unroll
        for (int w = 0; w < 8; w++) tot += st2[w * 128 + tid];
        st2[1024 + tid] = tot * (1.f / 128.f);
    }
    __syncthreads();
    {                                          // proj, 4 k-quarters
        int e = tid & 127, kq = tid >> 7;
        float a = 0.f;
        #pragma unroll 4
        for (int k = kq * 32; k < kq * 32 + 32; k++)
            a = fmaf(st2[1024 + k], pf[4608 + k * 128 + e], a);
        st2[1152 + kq * 128 + e] = a;
    }
    __syncthreads();
    if (tid < 128)
        st2[1664 + tid] = st2[1152 + tid] + st2[1280 + tid] + st2[1408 + tid] + st2[1536 + tid]
                        + pf[20992 + tid];
    __syncthreads();
    if (tid < 64) {
        float a1 = pf[29312 + tid];
        #pragma unroll 4
        for (int k = 0; k < 128; k++) a1 = fmaf(st2[1664 + k], pf[21120 + k * 64 + tid], a1);
        st2[1792 + tid] = fmaxf(a1, 0.f);
    }
    __syncthreads();
    if (tid < OUTD) {
        float a2 = pf[33216 + tid];
        #pragma unroll 4
        for (int k = 0; k < 64; k++) a2 = fmaf(st2[1792 + k], pf[29376 + k * OUTD + tid], a2);
        if (isbf) ((bf16*)outv)[b * OUTD + tid] = __float2bfloat16(a2);
        else      ((float*)outv)[b * OUTD + tid] = a2;
    }
}

extern "C" void kernel_launch(void* const* d_in, const int* in_sizes, int n_in,
                              void* d_out, int out_size, void* d_ws, size_t ws_size,
                              hipStream_t stream)
{
    float* ws = (float*)d_ws;
    float* pf = ws;                                // compact f32 params [0..33276)
    int*   flag = (int*)(ws + 33280);
    u16* WT16   = (u16*)(ws + 33536);              // 65,536
    u16* w1T16  = WT16 + 65536;                    // 131,072
    u16* w2T16  = w1T16 + 131072;                  // 131,072
    u16* WAb16  = w2T16 + 131072;                  // 8,192
    u16* Aw16   = WAb16 + 8192;                    // 16,384
    u16* ew2p   = Aw16 + 16384;                    // 16,384

    SrcPtrs S;
    for (int i = 0; i < 28; i++) S.p[i] = d_in[i];

    hipFuncSetAttribute((const void*)k_net,
                        hipFuncAttributeMaxDynamicSharedMemorySize, LDSB);

    k_prep<<<435, 256, 0, stream>>>(S, pf, WT16, w1T16, w2T16, WAb16, ew2p, Aw16, flag);
    k_net<<<BB, 512, LDSB, stream>>>(d_in[0], flag, pf,
                                     WT16, WAb16, Aw16, ew2p, w1T16, w2T16, d_out);
}

// Round 10
// 395.869 us; speedup vs baseline: 1.0142x; 1.0142x over previous
//
#include <hip/hip_runtime.h>
#include <hip/hip_bf16.h>

typedef __hip_bfloat16 bf16;
typedef unsigned short u16;
typedef __attribute__((ext_vector_type(8))) short bfrag;   // 8 bf16 = 4 VGPR
typedef __attribute__((ext_vector_type(4))) float cfrag;   // 4 f32 acc

union BF { bfrag v; u16 u[8]; unsigned w[4]; };
union CF { cfrag v; float f[4]; };

#define MFMA(a,b,c) __builtin_amdgcn_mfma_f32_16x16x32_bf16(a,b,c,0,0,0)

#define BB   256
#define NN   128
#define IND  9
#define HDD  128
#define LLY  4
#define OUTD 60
#define LOG2E 1.44269504f
#define STR  136                                  // u16 LDS row stride

__device__ __forceinline__ float b2f(bf16 v){ return __bfloat162float(v); }
__device__ __forceinline__ float u2f(u16 u){ return __uint_as_float(((unsigned)u) << 16); }
__device__ __forceinline__ u16 f2bf_bits(float f){
    unsigned u = __float_as_uint(f);
    return (u16)((u + 0x7FFFu + ((u >> 16) & 1u)) >> 16);   // RNE
}
__device__ __forceinline__ unsigned pk2(float a, float b){
    union { __hip_bfloat162 h; unsigned u; } c;
    c.h = __float22bfloat162_rn(make_float2(a, b));          // v_cvt_pk_bf16_f32
    return c.u;
}
__device__ __forceinline__ float wave_sum(float v){
    #pragma unroll
    for (int m = 32; m; m >>= 1) v += __shfl_xor(v, m, 64);
    return v;
}
__device__ __forceinline__ float ldin(const void* p, int i, bool isbf){
    return isbf ? b2f(((const bf16*)p)[i]) : ((const float*)p)[i];
}

struct SrcPtrs { const void* p[28]; };

// compact f32 params: cw0 cb1152 bg1280 bb1408 bm1536 bv1664 lng1792 lnb2304
// fb1:2816 fb2:3840 ng4352 nb4480 pw4608 pb20992 hw1:21120 hb1:29312 hw2:29376 hb2:33216
__device__ const int NCV_OFF[19] = {0,1152,1280,1408,1536,1664,1792,2304,2816,3840,
                                    4352,4480,4608,20992,21120,29312,29376,33216,33276};
__device__ const int NCV_SRC[18] = {1,2,3,4,5,6,10,11,13,15,16,17,18,19,20,21,22,23};

// ====== prep: detect + convert + LDS-tiled weight transposes + WAb + ew2 + Aw ======
// blocks: [0,131) cvt | [131,147) WT | [147,179) w1T | [179,211) w2T
//         [211,243) WAb | [243,307) ew2 | [307,435) Aw
__global__ __launch_bounds__(256) void k_prep(
    SrcPtrs S, float* __restrict__ pf,
    u16* __restrict__ WT, u16* __restrict__ w1T, u16* __restrict__ w2T,
    u16* __restrict__ WAb, u16* __restrict__ ew2, u16* __restrict__ Aw16,
    int* __restrict__ flagOut)
{
    __shared__ float tile[64][65];
    const unsigned* xw = (const unsigned*)S.p[0];
    int lane = threadIdx.x & 63;
    int cnt = 0;
    for (int i = lane; i < 512; i += 64) {
        float v = __uint_as_float((xw[i] & 0xFFFFu) << 16);
        if (!(fabsf(v) < 32.f)) cnt++;
    }
    bool isbf = wave_sum((float)cnt) < 16.f;
    if (blockIdx.x == 0 && threadIdx.x == 0) *flagOut = isbf ? 1 : 0;

    int blk = blockIdx.x, tid = threadIdx.x;
    if (blk < 131) {                               // small-param f32 convert
        int idx = blk * 256 + tid;
        if (idx < 33276) {
            int y = 17;
            #pragma unroll 1
            for (int t = 1; t < 18; t++) if (idx < NCV_OFF[t]) { y = t - 1; break; }
            pf[idx] = ldin(S.p[NCV_SRC[y]], idx - NCV_OFF[y], isbf);
        }
    } else if (blk < 211) {                        // tiled transposes: src[K][N] -> dst[N][K] bf16
        const void* src; u16* dst; int K, N, k0, n0;
        if (blk < 147) {                           // WT: per l 128x128, 4 tiles
            int t = blk - 131, l = t >> 2, tt = t & 3;
            src = (const char*)S.p[7] + (size_t)l * 16384 * (isbf ? 2 : 4);
            dst = WT + l * 16384; K = 128; N = 128; k0 = (tt >> 1) * 64; n0 = (tt & 1) * 64;
        } else if (blk < 179) {                    // w1T: per l 128x256, 8 tiles
            int t = blk - 147, l = t >> 3, tt = t & 7;
            src = (const char*)S.p[12] + (size_t)l * 32768 * (isbf ? 2 : 4);
            dst = w1T + l * 32768; K = 128; N = 256; k0 = (tt >> 2) * 64; n0 = (tt & 3) * 64;
        } else {                                   // w2T: per l 256x128, 8 tiles
            int t = blk - 179, l = t >> 3, tt = t & 7;
            src = (const char*)S.p[14] + (size_t)l * 32768 * (isbf ? 2 : 4);
            dst = w2T + l * 32768; K = 256; N = 128; k0 = (tt & 3) * 64; n0 = (tt >> 2) * 64;
        }
        int ty = tid >> 6, tx = tid & 63;
        #pragma unroll 4
        for (int i = 0; i < 16; i++) {
            int row = ty * 16 + i;
            tile[row][tx] = ldin(src, (k0 + row) * N + n0 + tx, isbf);
        }
        __syncthreads();
        #pragma unroll 4
        for (int i = 0; i < 16; i++) {
            int row = ty * 16 + i;
            dst[(n0 + row) * K + k0 + tx] = f2bf_bits(tile[tx][row]);
        }
    } else if (blk < 243) {                        // WAb[l][n16][k128] = (W @ [asrc|adst])^T
        int j = (blk - 211) * 256 + tid;           // 8192
        int l = j >> 11, r = j & 2047, n = r >> 7, k = r & 127;
        int h = n & 7;
        const void* ap = (n < 8) ? S.p[8] : S.p[9];
        float sacc = 0.f;
        #pragma unroll 1
        for (int d = 0; d < 16; d++)
            sacc += ldin(S.p[7], l * 16384 + k * 128 + h * 16 + d, isbf)
                  * ldin(ap, l * 128 + h * 16 + d, isbf);
        WAb[j] = f2bf_bits(sacc);
    } else if (blk < 307) {                        // ew2 = log2e*(mask? ewa : -1e30)
        int j = (blk - 243) * 256 + tid;
        float sav = ldin(S.p[24], j, isbf);
        float ewv = ldin(S.p[27], j, isbf);
        ew2[j] = f2bf_bits(sav > 0.f ? ewv * LOG2E : -1e30f);
    } else {                                       // Aw row-normalized * 0.4, bf16
        __shared__ float red[2];
        int i = blk - 307, j = tid & 127;
        float v = 0.f;
        if (tid < 128) {
            float wmv = ldin(S.p[25], i * 128 + j, isbf);
            float wpv = ldin(S.p[26], i * 128 + j, isbf);
            v = wmv / (1.f + __expf(-wpv));
            float sm = wave_sum(v);
            if ((tid & 63) == 0) red[tid >> 6] = sm;
        }
        __syncthreads();
        if (tid < 128) {
            float tot = red[0] + red[1];
            Aw16[i * 128 + j] = f2bf_bits(0.4f * v / (tot + 1e-5f));
        }
    }
}

// ====== whole-network megakernel: 1 block/graph, 512 thr = 8 waves, 16 rows/wave ======
// __launch_bounds__(512, 1): full 256+ VGPR budget -> ZERO spills (R9 post-mortem:
// the (512,2) 128-VGPR cap caused ~55 MB/dispatch scratch traffic = the 60 us/layer wall).
// LDS: U1 = h16 / gbuf (wave-private rows), U2 = hpT (cross-wave) / hid (wave-private),
// st2 = s2 f32 | t2 bf16 | invb f32 | head scratch. 79,872 B -> 1 block/CU.
#define LDSB (128*STR*2*2 + 2560*4)
__global__ __launch_bounds__(512, 1) void k_net(
    const void* __restrict__ xraw, const int* __restrict__ flag,
    const float* __restrict__ pf,
    const u16* __restrict__ WTg, const u16* __restrict__ WAbg,
    const u16* __restrict__ Awg, const u16* __restrict__ ew2g,
    const u16* __restrict__ w1Tg, const u16* __restrict__ w2Tg,
    void* __restrict__ outv)
{
    extern __shared__ __align__(16) char smem[];
    u16* U1 = (u16*)smem;                      // [128][STR]
    u16* U2 = U1 + 128 * STR;                  // [128][STR]
    float* st2  = (float*)(U2 + 128 * STR);    // 2560 f32
    float* s2   = st2;                         // [8][128] f32
    u16*   t2u  = (u16*)(st2 + 1024);          // [8][128] bf16
    float* invb = st2 + 1536;                  // [8][128] f32

    const int b = blockIdx.x;
    const int tid = threadIdx.x, lane = tid & 63, wv = tid >> 6;
    const int l15 = lane & 15, kg = lane >> 4;
    const int wrow = wv * 16;
    const int arow = wrow + l15;               // this lane's A-frag row
    const bool isbf = (*flag != 0);

    float hreg[8][4];                          // residual h, C-frag layout (own 16 rows)

    // ---------- embed: conv1d + BN + relu -> hreg + U1(bf16) ----------
    {
        float xr[4][IND];
        #pragma unroll
        for (int r = 0; r < 4; r++) {
            int bn = b * NN + wrow + kg * 4 + r;
            #pragma unroll
            for (int k = 0; k < IND; k++) xr[r][k] = ldin(xraw, bn * IND + k, isbf);
        }
        #pragma unroll 1
        for (int nt = 0; nt < 8; nt++) {
            int d = nt * 16 + l15;
            float cwreg[IND];
            #pragma unroll
            for (int k = 0; k < IND; k++) cwreg[k] = pf[d * IND + k];
            float scale = rsqrtf(pf[1664 + d] + 1e-5f) * pf[1280 + d];
            float bias  = pf[1408 + d] - pf[1536 + d] * scale;
            float cbd   = pf[1152 + d];
            #pragma unroll
            for (int r = 0; r < 4; r++) {
                float a = cbd;
                #pragma unroll
                for (int k = 0; k < IND; k++) a = fmaf(xr[r][k], cwreg[k], a);
                a = fmaxf(fmaf(a, scale, bias), 0.f);
                hreg[nt][r] = a;
                U1[(wrow + kg * 4 + r) * STR + d] = f2bf_bits(a);
            }
        }
    }

    // ---------- 4 layers ----------
    #pragma unroll 1
    for (int l = 0; l < LLY; l++) {
        const u16* WT  = WTg  + l * 16384;
        const u16* WAb = WAbg + l * 2048;
        const u16* w1T = w1Tg + l * 32768;
        const u16* w2T = w2Tg + l * 32768;
        const float* fb1 = pf + 2816 + l * 256;
        const float* fb2 = pf + 3840 + l * 128;
        const float* lng = pf + 1792 + l * 128;
        const float* lnb = pf + 2304 + l * 128;

        __syncthreads();                       // U2/s2/t2 free (prior cross-wave readers done)

        // P1: hp = h @ W (own rows -> hpT) + s,t = h @ (W·a)
        {
            CF acc[8], ast;
            #pragma unroll
            for (int r = 0; r < 4; r++) ast.f[r] = 0.f;
            #pragma unroll
            for (int nt = 0; nt < 8; nt++)
                #pragma unroll
                for (int r = 0; r < 4; r++) acc[nt].f[r] = 0.f;
            #pragma unroll
            for (int kk = 0; kk < 4; kk++) {
                bfrag af  = *(const bfrag*)&U1[arow * STR + kk*32 + kg*8];
                bfrag wab = *(const bfrag*)&WAb[l15 * 128 + kk*32 + kg*8];
                ast.v = MFMA(af, wab, ast.v);
                #pragma unroll
                for (int nt = 0; nt < 8; nt++) {
                    bfrag bw = *(const bfrag*)&WT[(nt*16 + l15) * 128 + kk*32 + kg*8];
                    acc[nt].v = MFMA(af, bw, acc[nt].v);
                }
            }
            #pragma unroll
            for (int nt = 0; nt < 8; nt++) {
                int col = nt*16 + l15;
                #pragma unroll
                for (int rp = 0; rp < 2; rp++) {
                    int row = wrow + kg*4 + rp*2;
                    *(unsigned*)&U2[col * STR + row] = pk2(acc[nt].f[rp*2], acc[nt].f[rp*2+1]);
                }
            }
            #pragma unroll
            for (int r = 0; r < 4; r++) {      // s (cols 0-7) f32, t (cols 8-15) bf16
                int node = wrow + kg*4 + r;
                float v = ast.f[r] * LOG2E;
                if (l15 < 8) s2[l15 * 128 + node] = v;
                else         t2u[(l15 - 8) * 128 + node] = f2bf_bits(v);
            }
        }
        __syncthreads();                       // hpT, s2, t2 ready

        // P2: strong attention, UNNORMALIZED P MFMA; 0.6*inv -> invb (own row)
        CF accS[8];
        #pragma unroll
        for (int nt = 0; nt < 8; nt++)
            #pragma unroll
            for (int r = 0; r < 4; r++) accS[nt].f[r] = 0.f;
        BF e2f[4];
        #pragma unroll
        for (int kk = 0; kk < 4; kk++)         // h-invariant edge bias, hoisted
            e2f[kk].v = *(const bfrag*)&ew2g[arow * 128 + kk*32 + kg*8];
        #pragma unroll 1
        for (int h = 0; h < 8; h++) {
            float sA = s2[h * 128 + arow];
            float sm = 0.f;
            #pragma unroll
            for (int kk = 0; kk < 4; kk++) {
                bfrag hb = *(const bfrag*)&U2[(h*16 + l15) * STR + kk*32 + kg*8];
                BF tb; tb.v = *(const bfrag*)&t2u[h * 128 + kk*32 + kg*8];
                BF pb;
                float p0[8];
                #pragma unroll
                for (int j = 0; j < 8; j++) {
                    float x2 = sA + u2f(tb.u[j]);
                    float lk = fmaxf(x2, 0.2f * x2);                  // log2e*leaky
                    float p = __builtin_amdgcn_exp2f(lk + u2f(e2f[kk].u[j]));
                    p0[j] = p; sm += p;
                }
                #pragma unroll
                for (int q = 0; q < 4; q++) pb.w[q] = pk2(p0[2*q], p0[2*q+1]);
                accS[h].v = MFMA(pb.v, hb, accS[h].v);                // no wait on sm chain
            }
            sm += __shfl_xor(sm, 16, 64);
            sm += __shfl_xor(sm, 32, 64);
            invb[h * 128 + arow] = 0.6f * __builtin_amdgcn_rcpf(sm);
        }
        // scale accS by 0.6*inv of each C-row (same wave's rows -> no barrier)
        #pragma unroll
        for (int h = 0; h < 8; h++) {
            const float4 iv = *(const float4*)&invb[h * 128 + wrow + kg*4];
            accS[h].f[0] *= iv.x; accS[h].f[1] *= iv.y;
            accS[h].f[2] *= iv.z; accS[h].f[3] *= iv.w;
        }

        // P3: weak accumulates into accS (Aw pre-scaled by 0.4)
        #pragma unroll
        for (int kk = 0; kk < 4; kk++) {
            bfrag awf = *(const bfrag*)&Awg[arow * 128 + kk*32 + kg*8];
            #pragma unroll
            for (int nt = 0; nt < 8; nt++) {
                bfrag hb2 = *(const bfrag*)&U2[(nt*16 + l15) * STR + kk*32 + kg*8];
                accS[nt].v = MFMA(awf, hb2, accS[nt].v);
            }
        }

        // P4: g = relu(acc), LN -> gbuf (U1, own rows; U1's h16 dead after P1)
        #pragma unroll
        for (int r = 0; r < 4; r++) {
            float s1 = 0.f, sq = 0.f;
            #pragma unroll
            for (int nt = 0; nt < 8; nt++) {
                float x = fmaxf(accS[nt].f[r], 0.f);
                accS[nt].f[r] = x; s1 += x; sq = fmaf(x, x, sq);
            }
            #pragma unroll
            for (int m = 1; m <= 8; m <<= 1) { s1 += __shfl_xor(s1, m, 64); sq += __shfl_xor(sq, m, 64); }
            float mu = s1 * (1.f / 128.f);
            float var = sq * (1.f / 128.f) - mu * mu;
            float rs = rsqrtf(fmaxf(var, 0.f) + 1e-5f);
            #pragma unroll
            for (int nt = 0; nt < 8; nt++) {
                int col = nt*16 + l15;
                U1[(wrow + kg*4 + r) * STR + col] =
                    f2bf_bits(fmaf((accS[nt].f[r] - mu) * rs, lng[col], lnb[col]));
            }
        }

        __syncthreads();                       // all waves past P3's cross-wave hpT reads
        // P5: FFN (own rows); hid overwrites U2
        CF acc2[8];
        #pragma unroll
        for (int nt = 0; nt < 8; nt++)
            #pragma unroll
            for (int r = 0; r < 4; r++) acc2[nt].f[r] = 0.f;
        #pragma unroll 1
        for (int nh = 0; nh < 2; nh++) {
            CF a1[8];
            #pragma unroll
            for (int nt = 0; nt < 8; nt++)
                #pragma unroll
                for (int r = 0; r < 4; r++) a1[nt].f[r] = 0.f;
            #pragma unroll
            for (int kk = 0; kk < 4; kk++) {
                bfrag gf = *(const bfrag*)&U1[arow * STR + kk*32 + kg*8];
                #pragma unroll
                for (int nt = 0; nt < 8; nt++) {
                    bfrag wf = *(const bfrag*)&w1T[(nh*128 + nt*16 + l15) * 128 + kk*32 + kg*8];
                    a1[nt].v = MFMA(gf, wf, a1[nt].v);
                }
            }
            #pragma unroll
            for (int nt = 0; nt < 8; nt++) {
                int col = nt*16 + l15;
                float b1v = fb1[nh*128 + col];
                #pragma unroll
                for (int r = 0; r < 4; r++)
                    U2[(wrow + kg*4 + r) * STR + col] = f2bf_bits(fmaxf(a1[nt].f[r] + b1v, 0.f));
            }
            #pragma unroll
            for (int kk = 0; kk < 4; kk++) {
                bfrag hf = *(const bfrag*)&U2[arow * STR + kk*32 + kg*8];
                #pragma unroll
                for (int nt = 0; nt < 8; nt++) {
                    bfrag wf = *(const bfrag*)&w2T[(nt*16 + l15) * 256 + nh*128 + kk*32 + kg*8];
                    acc2[nt].v = MFMA(hf, wf, acc2[nt].v);
                }
            }
        }

        // epilogue: h += ffn + b2 (regs); rebuild U1 bf16 for next layer
        #pragma unroll
        for (int nt = 0; nt < 8; nt++) {
            int col = nt*16 + l15;
            float b2v = fb2[col];
            #pragma unroll
            for (int r = 0; r < 4; r++) {
                hreg[nt][r] += acc2[nt].f[r] + b2v;
                if (l < LLY - 1)
                    U1[(wrow + kg*4 + r) * STR + col] = f2bf_bits(hreg[nt][r]);
            }
        }
    }

    // ---------- final LN + node-sum (proj commutes with mean) + head ----------
    const float* ng = pf + 4352;
    const float* nb = pf + 4480;
    float pacc[8];
    #pragma unroll
    for (int nt = 0; nt < 8; nt++) pacc[nt] = 0.f;
    #pragma unroll
    for (int r = 0; r < 4; r++) {
        float s1 = 0.f, sq = 0.f;
        #pragma unroll
        for (int nt = 0; nt < 8; nt++) { float x = hreg[nt][r]; s1 += x; sq = fmaf(x, x, sq); }
        #pragma unroll
        for (int m = 1; m <= 8; m <<= 1) { s1 += __shfl_xor(s1, m, 64); sq += __shfl_xor(sq, m, 64); }
        float mu = s1 * (1.f / 128.f);
        float var = sq * (1.f / 128.f) - mu * mu;
        float rs = rsqrtf(fmaxf(var, 0.f) + 1e-5f);
        #pragma unroll
        for (int nt = 0; nt < 8; nt++)
            pacc[nt] += fmaf((hreg[nt][r] - mu) * rs, ng[nt*16 + l15], nb[nt*16 + l15]);
    }
    #pragma unroll
    for (int nt = 0; nt < 8; nt++) {           // sum over this wave's kg groups
        pacc[nt] += __shfl_xor(pacc[nt], 16, 64);
        pacc[nt] += __shfl_xor(pacc[nt], 32, 64);
    }
    __syncthreads();                           // s2/t2/invb dead -> reuse st2
    if (kg == 0) {
        #pragma unroll
        for (int nt = 0; nt < 8; nt++) st2[wv * 128 + nt*16 + l15] = pacc[nt];
    }
    __syncthreads();
    if (tid < 128) {                           // pooled mean
        float tot = 0.f;
        #pragma unroll
        for (int w = 0; w < 8; w++) tot += st2[w * 128 + tid];
        st2[1024 + tid] = tot * (1.f / 128.f);
    }
    __syncthreads();
    {                                          // proj, 4 k-quarters
        int e = tid & 127, kq = tid >> 7;
        float a = 0.f;
        #pragma unroll 4
        for (int k = kq * 32; k < kq * 32 + 32; k++)
            a = fmaf(st2[1024 + k], pf[4608 + k * 128 + e], a);
        st2[1152 + kq * 128 + e] = a;
    }
    __syncthreads();
    if (tid < 128)
        st2[1664 + tid] = st2[1152 + tid] + st2[1280 + tid] + st2[1408 + tid] + st2[1536 + tid]
                        + pf[20992 + tid];
    __syncthreads();
    if (tid < 64) {
        float a1 = pf[29312 + tid];
        #pragma unroll 4
        for (int k = 0; k < 128; k++) a1 = fmaf(st2[1664 + k], pf[21120 + k * 64 + tid], a1);
        st2[1792 + tid] = fmaxf(a1, 0.f);
    }
    __syncthreads();
    if (tid < OUTD) {
        float a2 = pf[33216 + tid];
        #pragma unroll 4
        for (int k = 0; k < 64; k++) a2 = fmaf(st2[1792 + k], pf[29376 + k * OUTD + tid], a2);
        if (isbf) ((bf16*)outv)[b * OUTD + tid] = __float2bfloat16(a2);
        else      ((float*)outv)[b * OUTD + tid] = a2;
    }
}

extern "C" void kernel_launch(void* const* d_in, const int* in_sizes, int n_in,
                              void* d_out, int out_size, void* d_ws, size_t ws_size,
                              hipStream_t stream)
{
    float* ws = (float*)d_ws;
    float* pf = ws;                                // compact f32 params [0..33276)
    int*   flag = (int*)(ws + 33280);
    u16* WT16   = (u16*)(ws + 33536);              // 65,536
    u16* w1T16  = WT16 + 65536;                    // 131,072
    u16* w2T16  = w1T16 + 131072;                  // 131,072
    u16* WAb16  = w2T16 + 131072;                  // 8,192
    u16* Aw16   = WAb16 + 8192;                    // 16,384
    u16* ew2p   = Aw16 + 16384;                    // 16,384

    SrcPtrs S;
    for (int i = 0; i < 28; i++) S.p[i] = d_in[i];

    hipFuncSetAttribute((const void*)k_net,
                        hipFuncAttributeMaxDynamicSharedMemorySize, LDSB);

    k_prep<<<435, 256, 0, stream>>>(S, pf, WT16, w1T16, w2T16, WAb16, ew2p, Aw16, flag);
    k_net<<<BB, 512, LDSB, stream>>>(d_in[0], flag, pf,
                                     WT16, WAb16, Aw16, ew2p, w1T16, w2T16, d_out);
}

// Round 11
// 377.253 us; speedup vs baseline: 1.0643x; 1.0493x over previous
//
#include <hip/hip_runtime.h>
#include <hip/hip_bf16.h>

typedef __hip_bfloat16 bf16;
typedef unsigned short u16;
typedef __attribute__((ext_vector_type(8))) short bfrag;   // 8 bf16 = 4 VGPR
typedef __attribute__((ext_vector_type(4))) float cfrag;   // 4 f32 acc

union BF { bfrag v; u16 u[8]; unsigned w[4]; };
union CF { cfrag v; float f[4]; };

#define MFMA(a,b,c) __builtin_amdgcn_mfma_f32_16x16x32_bf16(a,b,c,0,0,0)

#define BB   256
#define NN   128
#define IND  9
#define HDD  128
#define LLY  4
#define OUTD 60
#define LOG2E 1.44269504f
#define STR  136                                  // u16 LDS row stride

__device__ __forceinline__ float b2f(bf16 v){ return __bfloat162float(v); }
__device__ __forceinline__ float u2f(u16 u){ return __uint_as_float(((unsigned)u) << 16); }
__device__ __forceinline__ u16 f2bf_bits(float f){
    unsigned u = __float_as_uint(f);
    return (u16)((u + 0x7FFFu + ((u >> 16) & 1u)) >> 16);   // RNE
}
__device__ __forceinline__ unsigned pk2(float a, float b){
    union { __hip_bfloat162 h; unsigned u; } c;
    c.h = __float22bfloat162_rn(make_float2(a, b));          // v_cvt_pk_bf16_f32
    return c.u;
}
__device__ __forceinline__ float wave_sum(float v){
    #pragma unroll
    for (int m = 32; m; m >>= 1) v += __shfl_xor(v, m, 64);
    return v;
}
__device__ __forceinline__ float ldin(const void* p, int i, bool isbf){
    return isbf ? b2f(((const bf16*)p)[i]) : ((const float*)p)[i];
}

struct SrcPtrs { const void* p[28]; };

// compact f32 params: cw0 cb1152 bg1280 bb1408 bm1536 bv1664 lng1792 lnb2304
// fb1:2816 fb2:3840 ng4352 nb4480 pw4608 pb20992 hw1:21120 hb1:29312 hw2:29376 hb2:33216
__device__ const int NCV_OFF[19] = {0,1152,1280,1408,1536,1664,1792,2304,2816,3840,
                                    4352,4480,4608,20992,21120,29312,29376,33216,33276};
__device__ const int NCV_SRC[18] = {1,2,3,4,5,6,10,11,13,15,16,17,18,19,20,21,22,23};

// ====== prep: detect + convert + LDS-tiled weight transposes + WAb + ew2 + Aw ======
__global__ __launch_bounds__(256) void k_prep(
    SrcPtrs S, float* __restrict__ pf,
    u16* __restrict__ WT, u16* __restrict__ w1T, u16* __restrict__ w2T,
    u16* __restrict__ WAb, u16* __restrict__ ew2, u16* __restrict__ Aw16,
    int* __restrict__ flagOut)
{
    __shared__ float tile[64][65];
    const unsigned* xw = (const unsigned*)S.p[0];
    int lane = threadIdx.x & 63;
    int cnt = 0;
    for (int i = lane; i < 512; i += 64) {
        float v = __uint_as_float((xw[i] & 0xFFFFu) << 16);
        if (!(fabsf(v) < 32.f)) cnt++;
    }
    bool isbf = wave_sum((float)cnt) < 16.f;
    if (blockIdx.x == 0 && threadIdx.x == 0) *flagOut = isbf ? 1 : 0;

    int blk = blockIdx.x, tid = threadIdx.x;
    if (blk < 131) {                               // small-param f32 convert
        int idx = blk * 256 + tid;
        if (idx < 33276) {
            int y = 17;
            #pragma unroll 1
            for (int t = 1; t < 18; t++) if (idx < NCV_OFF[t]) { y = t - 1; break; }
            pf[idx] = ldin(S.p[NCV_SRC[y]], idx - NCV_OFF[y], isbf);
        }
    } else if (blk < 211) {                        // tiled transposes: src[K][N] -> dst[N][K] bf16
        const void* src; u16* dst; int K, N, k0, n0;
        if (blk < 147) {                           // WT
            int t = blk - 131, l = t >> 2, tt = t & 3;
            src = (const char*)S.p[7] + (size_t)l * 16384 * (isbf ? 2 : 4);
            dst = WT + l * 16384; K = 128; N = 128; k0 = (tt >> 1) * 64; n0 = (tt & 1) * 64;
        } else if (blk < 179) {                    // w1T
            int t = blk - 147, l = t >> 3, tt = t & 7;
            src = (const char*)S.p[12] + (size_t)l * 32768 * (isbf ? 2 : 4);
            dst = w1T + l * 32768; K = 128; N = 256; k0 = (tt >> 2) * 64; n0 = (tt & 3) * 64;
        } else {                                   // w2T
            int t = blk - 179, l = t >> 3, tt = t & 7;
            src = (const char*)S.p[14] + (size_t)l * 32768 * (isbf ? 2 : 4);
            dst = w2T + l * 32768; K = 256; N = 128; k0 = (tt & 3) * 64; n0 = (tt >> 2) * 64;
        }
        int ty = tid >> 6, tx = tid & 63;
        #pragma unroll 4
        for (int i = 0; i < 16; i++) {
            int row = ty * 16 + i;
            tile[row][tx] = ldin(src, (k0 + row) * N + n0 + tx, isbf);
        }
        __syncthreads();
        #pragma unroll 4
        for (int i = 0; i < 16; i++) {
            int row = ty * 16 + i;
            dst[(n0 + row) * K + k0 + tx] = f2bf_bits(tile[tx][row]);
        }
    } else if (blk < 243) {                        // WAb[l][n16][k128] = (W @ [asrc|adst])^T
        int j = (blk - 211) * 256 + tid;
        int l = j >> 11, r = j & 2047, n = r >> 7, k = r & 127;
        int h = n & 7;
        const void* ap = (n < 8) ? S.p[8] : S.p[9];
        float sacc = 0.f;
        #pragma unroll 1
        for (int d = 0; d < 16; d++)
            sacc += ldin(S.p[7], l * 16384 + k * 128 + h * 16 + d, isbf)
                  * ldin(ap, l * 128 + h * 16 + d, isbf);
        WAb[j] = f2bf_bits(sacc);
    } else if (blk < 307) {                        // ew2 = log2e*(mask? ewa : -1e30)
        int j = (blk - 243) * 256 + tid;
        float sav = ldin(S.p[24], j, isbf);
        float ewv = ldin(S.p[27], j, isbf);
        ew2[j] = f2bf_bits(sav > 0.f ? ewv * LOG2E : -1e30f);
    } else {                                       // Aw row-normalized * 0.4, bf16
        __shared__ float red[2];
        int i = blk - 307, j = tid & 127;
        float v = 0.f;
        if (tid < 128) {
            float wmv = ldin(S.p[25], i * 128 + j, isbf);
            float wpv = ldin(S.p[26], i * 128 + j, isbf);
            v = wmv / (1.f + __expf(-wpv));
            float sm = wave_sum(v);
            if ((tid & 63) == 0) red[tid >> 6] = sm;
        }
        __syncthreads();
        if (tid < 128) {
            float tot = red[0] + red[1];
            Aw16[i * 128 + j] = f2bf_bits(0.4f * v / (tot + 1e-5f));
        }
    }
}

// ====== whole-network megakernel: 1 block/graph, 512 thr = 8 waves, 16 rows/wave ======
// Register-pressure-disciplined (R10 post-mortem: MFMA kernels spill ~50 MB scratch at
// the 128-VGPR cap). Residual h in LDS f32; weak merged into accS; nt-split P1/FFN1.
// LDS: U1 [128][STR] u16 (h16/gbuf, own rows) | U2 [128][STR] u16 (hpT cross-wave / hid own)
//      hres [128][132] f32 (own rows) | st2 2560 f32 (s2|t2|head). 147,456 B -> 1 block/CU.
#define LDSB (128*STR*2*2 + 128*132*4 + 2560*4)
__global__ __launch_bounds__(512, 1) void k_net(
    const void* __restrict__ xraw, const int* __restrict__ flag,
    const float* __restrict__ pf,
    const u16* __restrict__ WTg, const u16* __restrict__ WAbg,
    const u16* __restrict__ Awg, const u16* __restrict__ ew2g,
    const u16* __restrict__ w1Tg, const u16* __restrict__ w2Tg,
    void* __restrict__ outv)
{
    extern __shared__ __align__(16) char smem[];
    u16* U1 = (u16*)smem;                      // [128][STR]
    u16* U2 = U1 + 128 * STR;                  // [128][STR]
    float* hres = (float*)(U2 + 128 * STR);    // [128][132]
    float* st2  = hres + 128 * 132;            // 2560 f32
    float* s2   = st2;                         // [8][128] f32
    u16*   t2u  = (u16*)(st2 + 1024);          // [8][128] bf16

    const int b = blockIdx.x;
    const int tid = threadIdx.x, lane = tid & 63, wv = tid >> 6;
    const int l15 = lane & 15, kg = lane >> 4;
    const int wrow = wv * 16;
    const int arow = wrow + l15;               // this lane's A-frag row
    const bool isbf = (*flag != 0);

    // ---------- embed: conv1d + BN + relu -> hres + U1(bf16) ----------
    {
        float xr[4][IND];
        #pragma unroll
        for (int r = 0; r < 4; r++) {
            int bn = b * NN + wrow + kg * 4 + r;
            #pragma unroll
            for (int k = 0; k < IND; k++) xr[r][k] = ldin(xraw, bn * IND + k, isbf);
        }
        #pragma unroll 1
        for (int nt = 0; nt < 8; nt++) {
            int d = nt * 16 + l15;
            float cwreg[IND];
            #pragma unroll
            for (int k = 0; k < IND; k++) cwreg[k] = pf[d * IND + k];
            float scale = rsqrtf(pf[1664 + d] + 1e-5f) * pf[1280 + d];
            float bias  = pf[1408 + d] - pf[1536 + d] * scale;
            float cbd   = pf[1152 + d];
            #pragma unroll
            for (int r = 0; r < 4; r++) {
                float a = cbd;
                #pragma unroll
                for (int k = 0; k < IND; k++) a = fmaf(xr[r][k], cwreg[k], a);
                a = fmaxf(fmaf(a, scale, bias), 0.f);
                int row = wrow + kg * 4 + r;
                hres[row * 132 + d] = a;
                U1[row * STR + d] = f2bf_bits(a);
            }
        }
    }

    // ---------- 4 layers ----------
    #pragma unroll 1
    for (int l = 0; l < LLY; l++) {
        const u16* WT  = WTg  + l * 16384;
        const u16* WAb = WAbg + l * 2048;
        const u16* w1T = w1Tg + l * 32768;
        const u16* w2T = w2Tg + l * 32768;
        const float* fb1 = pf + 2816 + l * 256;
        const float* fb2 = pf + 3840 + l * 128;
        const float* lng = pf + 1792 + l * 128;
        const float* lnb = pf + 2304 + l * 128;

        __syncthreads();                       // U2/s2/t2 free (prior cross-wave readers done)

        // ---- P1: hp = h @ W (own rows -> hpT), nt-split 4+4; s,t = h @ (W·a) ----
        #pragma unroll 1
        for (int pass = 0; pass < 2; pass++) {
            CF acc[4], ast;
            #pragma unroll
            for (int q = 0; q < 4; q++)
                #pragma unroll
                for (int r = 0; r < 4; r++) acc[q].f[r] = 0.f;
            #pragma unroll
            for (int r = 0; r < 4; r++) ast.f[r] = 0.f;
            #pragma unroll
            for (int kk = 0; kk < 4; kk++) {
                bfrag af = *(const bfrag*)&U1[arow * STR + kk*32 + kg*8];
                if (pass == 0) {
                    bfrag wab = *(const bfrag*)&WAb[l15 * 128 + kk*32 + kg*8];
                    ast.v = MFMA(af, wab, ast.v);
                }
                #pragma unroll
                for (int q = 0; q < 4; q++) {
                    bfrag bw = *(const bfrag*)&WT[((pass*4+q)*16 + l15) * 128 + kk*32 + kg*8];
                    acc[q].v = MFMA(af, bw, acc[q].v);
                }
            }
            #pragma unroll
            for (int q = 0; q < 4; q++) {
                int col = (pass*4+q)*16 + l15;
                #pragma unroll
                for (int rp = 0; rp < 2; rp++) {
                    int row = wrow + kg*4 + rp*2;
                    *(unsigned*)&U2[col * STR + row] = pk2(acc[q].f[rp*2], acc[q].f[rp*2+1]);
                }
            }
            if (pass == 0) {
                #pragma unroll
                for (int r = 0; r < 4; r++) {  // s (cols 0-7) f32, t (cols 8-15) bf16
                    int node = wrow + kg*4 + r;
                    float v = ast.f[r] * LOG2E;
                    if (l15 < 8) s2[l15 * 128 + node] = v;
                    else         t2u[(l15 - 8) * 128 + node] = f2bf_bits(v);
                }
            }
        }
        __syncthreads();                       // hpT, s2, t2 ready

        // ---- P2: weak FIRST into accS (Aw pre-scaled 0.4), nt-split ----
        CF accS[8];
        #pragma unroll
        for (int nt = 0; nt < 8; nt++)
            #pragma unroll
            for (int r = 0; r < 4; r++) accS[nt].f[r] = 0.f;
        #pragma unroll 1
        for (int pass = 0; pass < 2; pass++) {
            #pragma unroll
            for (int kk = 0; kk < 4; kk++) {
                bfrag awf = *(const bfrag*)&Awg[arow * 128 + kk*32 + kg*8];
                #pragma unroll
                for (int q = 0; q < 4; q++) {
                    int nt = pass*4 + q;
                    bfrag hb2 = *(const bfrag*)&U2[(nt*16 + l15) * STR + kk*32 + kg*8];
                    accS[nt].v = MFMA(awf, hb2, accS[nt].v);
                }
            }
        }

        // ---- P3: attention, normalized P (scaled by 0.6/sm), accumulates into accS ----
        BF e2f[4];
        #pragma unroll
        for (int kk = 0; kk < 4; kk++)
            e2f[kk].v = *(const bfrag*)&ew2g[arow * 128 + kk*32 + kg*8];
        #pragma unroll 1
        for (int h = 0; h < 8; h++) {
            bfrag hb[4];
            #pragma unroll
            for (int kk = 0; kk < 4; kk++)
                hb[kk] = *(const bfrag*)&U2[(h*16 + l15) * STR + kk*32 + kg*8];
            float sA = s2[h * 128 + arow];
            float pv[4][8];
            float sm = 0.f;
            #pragma unroll
            for (int kk = 0; kk < 4; kk++) {
                BF tb; tb.v = *(const bfrag*)&t2u[h * 128 + kk*32 + kg*8];
                #pragma unroll
                for (int j = 0; j < 8; j++) {
                    float x2 = sA + u2f(tb.u[j]);
                    float lk = fmaxf(x2, 0.2f * x2);                  // log2e*leaky
                    float p = __builtin_amdgcn_exp2f(lk + u2f(e2f[kk].u[j]));
                    pv[kk][j] = p; sm += p;
                }
            }
            sm += __shfl_xor(sm, 16, 64);
            sm += __shfl_xor(sm, 32, 64);
            float sc = 0.6f * __builtin_amdgcn_rcpf(sm);
            #pragma unroll
            for (int kk = 0; kk < 4; kk++) {
                BF pb;
                #pragma unroll
                for (int q = 0; q < 4; q++)
                    pb.w[q] = pk2(pv[kk][2*q] * sc, pv[kk][2*q+1] * sc);
                accS[h].v = MFMA(pb.v, hb[kk], accS[h].v);
            }
        }

        // ---- P4: g = relu(accS), LN -> U1 (own rows) ----
        #pragma unroll
        for (int r = 0; r < 4; r++) {
            float s1 = 0.f, sq = 0.f;
            #pragma unroll
            for (int nt = 0; nt < 8; nt++) {
                float x = fmaxf(accS[nt].f[r], 0.f);
                accS[nt].f[r] = x; s1 += x; sq = fmaf(x, x, sq);
            }
            #pragma unroll
            for (int m = 1; m <= 8; m <<= 1) { s1 += __shfl_xor(s1, m, 64); sq += __shfl_xor(sq, m, 64); }
            float mu = s1 * (1.f / 128.f);
            float var = sq * (1.f / 128.f) - mu * mu;
            float rs = rsqrtf(fmaxf(var, 0.f) + 1e-5f);
            #pragma unroll
            for (int nt = 0; nt < 8; nt++) {
                int col = nt*16 + l15;
                U1[(wrow + kg*4 + r) * STR + col] =
                    f2bf_bits(fmaf((accS[nt].f[r] - mu) * rs, lng[col], lnb[col]));
            }
        }

        __syncthreads();                       // all waves done with cross-wave hpT reads

        // ---- P5: FFN; FFN1 nt-split 4+4 per nh-half; hid in U2 (own rows) ----
        CF acc2[8];
        #pragma unroll
        for (int nt = 0; nt < 8; nt++)
            #pragma unroll
            for (int r = 0; r < 4; r++) acc2[nt].f[r] = 0.f;
        #pragma unroll 1
        for (int nh = 0; nh < 2; nh++) {
            #pragma unroll 1
            for (int pass = 0; pass < 2; pass++) {
                CF a1[4];
                #pragma unroll
                for (int q = 0; q < 4; q++)
                    #pragma unroll
                    for (int r = 0; r < 4; r++) a1[q].f[r] = 0.f;
                #pragma unroll
                for (int kk = 0; kk < 4; kk++) {
                    bfrag gf = *(const bfrag*)&U1[arow * STR + kk*32 + kg*8];
                    #pragma unroll
                    for (int q = 0; q < 4; q++) {
                        int n = nh*128 + (pass*4+q)*16 + l15;
                        bfrag wf = *(const bfrag*)&w1T[n * 128 + kk*32 + kg*8];
                        a1[q].v = MFMA(gf, wf, a1[q].v);
                    }
                }
                #pragma unroll
                for (int q = 0; q < 4; q++) {
                    int col = (pass*4+q)*16 + l15;
                    float b1v = fb1[nh*128 + col];
                    #pragma unroll
                    for (int r = 0; r < 4; r++)
                        U2[(wrow + kg*4 + r) * STR + col] =
                            f2bf_bits(fmaxf(a1[q].f[r] + b1v, 0.f));
                }
            }
            #pragma unroll
            for (int kk = 0; kk < 4; kk++) {   // FFN2: hid half nh (own rows)
                bfrag hf = *(const bfrag*)&U2[arow * STR + kk*32 + kg*8];
                #pragma unroll
                for (int nt = 0; nt < 8; nt++) {
                    bfrag wf = *(const bfrag*)&w2T[(nt*16 + l15) * 256 + nh*128 + kk*32 + kg*8];
                    acc2[nt].v = MFMA(hf, wf, acc2[nt].v);
                }
            }
        }

        // ---- epilogue: hres += ffn + b2; rebuild U1 h16 for next layer ----
        #pragma unroll
        for (int nt = 0; nt < 8; nt++) {
            int col = nt*16 + l15;
            float b2v = fb2[col];
            #pragma unroll
            for (int r = 0; r < 4; r++) {
                int row = wrow + kg*4 + r;
                float hv = hres[row * 132 + col] + acc2[nt].f[r] + b2v;
                hres[row * 132 + col] = hv;
                if (l < LLY - 1) U1[row * STR + col] = f2bf_bits(hv);
            }
        }
    }

    // ---------- final LN + node-sum (proj commutes with mean) + head ----------
    const float* ng = pf + 4352;
    const float* nb = pf + 4480;
    float pacc[8];
    #pragma unroll
    for (int nt = 0; nt < 8; nt++) pacc[nt] = 0.f;
    #pragma unroll
    for (int r = 0; r < 4; r++) {
        int row = wrow + kg*4 + r;
        float hvv[8];
        float s1 = 0.f, sq = 0.f;
        #pragma unroll
        for (int nt = 0; nt < 8; nt++) {
            float x = hres[row * 132 + nt*16 + l15];
            hvv[nt] = x; s1 += x; sq = fmaf(x, x, sq);
        }
        #pragma unroll
        for (int m = 1; m <= 8; m <<= 1) { s1 += __shfl_xor(s1, m, 64); sq += __shfl_xor(sq, m, 64); }
        float mu = s1 * (1.f / 128.f);
        float var = sq * (1.f / 128.f) - mu * mu;
        float rs = rsqrtf(fmaxf(var, 0.f) + 1e-5f);
        #pragma unroll
        for (int nt = 0; nt < 8; nt++)
            pacc[nt] += fmaf((hvv[nt] - mu) * rs, ng[nt*16 + l15], nb[nt*16 + l15]);
    }
    #pragma unroll
    for (int nt = 0; nt < 8; nt++) {
        pacc[nt] += __shfl_xor(pacc[nt], 16, 64);
        pacc[nt] += __shfl_xor(pacc[nt], 32, 64);
    }
    __syncthreads();                           // st2 dead -> reuse
    if (kg == 0) {
        #pragma unroll
        for (int nt = 0; nt < 8; nt++) st2[wv * 128 + nt*16 + l15] = pacc[nt];
    }
    __syncthreads();
    if (tid < 128) {                           // pooled mean
        float tot = 0.f;
        #pragma unroll
        for (int w = 0; w < 8; w++) tot += st2[w * 128 + tid];
        st2[1024 + tid] = tot * (1.f / 128.f);
    }
    __syncthreads();
    {                                          // proj, 4 k-quarters
        int e = tid & 127, kq = tid >> 7;
        float a = 0.f;
        #pragma unroll 4
        for (int k = kq * 32; k < kq * 32 + 32; k++)
            a = fmaf(st2[1024 + k], pf[4608 + k * 128 + e], a);
        st2[1152 + kq * 128 + e] = a;
    }
    __syncthreads();
    if (tid < 128)
        st2[1664 + tid] = st2[1152 + tid] + st2[1280 + tid] + st2[1408 + tid] + st2[1536 + tid]
                        + pf[20992 + tid];
    __syncthreads();
    if (tid < 64) {
        float a1 = pf[29312 + tid];
        #pragma unroll 4
        for (int k = 0; k < 128; k++) a1 = fmaf(st2[1664 + k], pf[21120 + k * 64 + tid], a1);
        st2[1792 + tid] = fmaxf(a1, 0.f);
    }
    __syncthreads();
    if (tid < OUTD) {
        float a2 = pf[33216 + tid];
        #pragma unroll 4
        for (int k = 0; k < 64; k++) a2 = fmaf(st2[1792 + k], pf[29376 + k * OUTD + tid], a2);
        if (isbf) ((bf16*)outv)[b * OUTD + tid] = __float2bfloat16(a2);
        else      ((float*)outv)[b * OUTD + tid] = a2;
    }
}

extern "C" void kernel_launch(void* const* d_in, const int* in_sizes, int n_in,
                              void* d_out, int out_size, void* d_ws, size_t ws_size,
                              hipStream_t stream)
{
    float* ws = (float*)d_ws;
    float* pf = ws;                                // compact f32 params [0..33276)
    int*   flag = (int*)(ws + 33280);
    u16* WT16   = (u16*)(ws + 33536);              // 65,536
    u16* w1T16  = WT16 + 65536;                    // 131,072
    u16* w2T16  = w1T16 + 131072;                  // 131,072
    u16* WAb16  = w2T16 + 131072;                  // 8,192
    u16* Aw16   = WAb16 + 8192;                    // 16,384
    u16* ew2p   = Aw16 + 16384;                    // 16,384

    SrcPtrs S;
    for (int i = 0; i < 28; i++) S.p[i] = d_in[i];

    hipFuncSetAttribute((const void*)k_net,
                        hipFuncAttributeMaxDynamicSharedMemorySize, LDSB);

    k_prep<<<435, 256, 0, stream>>>(S, pf, WT16, w1T16, w2T16, WAb16, ew2p, Aw16, flag);
    k_net<<<BB, 512, LDSB, stream>>>(d_in[0], flag, pf,
                                     WT16, WAb16, Aw16, ew2p, w1T16, w2T16, d_out);
}

// Round 12
// 353.333 us; speedup vs baseline: 1.1363x; 1.0677x over previous
//
#include <hip/hip_runtime.h>
#include <hip/hip_bf16.h>

typedef __hip_bfloat16 bf16;
typedef unsigned short u16;
typedef __attribute__((ext_vector_type(8))) short bfrag;   // 8 bf16 = 4 VGPR
typedef __attribute__((ext_vector_type(4))) float cfrag;   // 4 f32 acc

union BF { bfrag v; u16 u[8]; unsigned w[4]; };
union CF { cfrag v; float f[4]; };

#define MFMA(a,b,c) __builtin_amdgcn_mfma_f32_16x16x32_bf16(a,b,c,0,0,0)

#define BB   256
#define NN   128
#define IND  9
#define HDD  128
#define LLY  4
#define OUTD 60
#define LOG2E 1.44269504f
#define STR  136                                  // u16 LDS row stride

__device__ __forceinline__ float b2f(bf16 v){ return __bfloat162float(v); }
__device__ __forceinline__ float u2f(u16 u){ return __uint_as_float(((unsigned)u) << 16); }
__device__ __forceinline__ u16 f2bf_bits(float f){
    unsigned u = __float_as_uint(f);
    return (u16)((u + 0x7FFFu + ((u >> 16) & 1u)) >> 16);   // RNE
}
__device__ __forceinline__ unsigned pk2(float a, float b){
    union { __hip_bfloat162 h; unsigned u; } c;
    c.h = __float22bfloat162_rn(make_float2(a, b));          // v_cvt_pk_bf16_f32
    return c.u;
}
__device__ __forceinline__ float wave_sum(float v){
    #pragma unroll
    for (int m = 32; m; m >>= 1) v += __shfl_xor(v, m, 64);
    return v;
}
__device__ __forceinline__ float ldin(const void* p, int i, bool isbf){
    return isbf ? b2f(((const bf16*)p)[i]) : ((const float*)p)[i];
}

struct SrcPtrs { const void* p[28]; };

// compact f32 params: cw0 cb1152 bg1280 bb1408 bm1536 bv1664 lng1792 lnb2304
// fb1:2816 fb2:3840 ng4352 nb4480 pw4608 pb20992 hw1:21120 hb1:29312 hw2:29376 hb2:33216
__device__ const int NCV_OFF[19] = {0,1152,1280,1408,1536,1664,1792,2304,2816,3840,
                                    4352,4480,4608,20992,21120,29312,29376,33216,33276};
__device__ const int NCV_SRC[18] = {1,2,3,4,5,6,10,11,13,15,16,17,18,19,20,21,22,23};

// ====== prep: detect + convert + LDS-tiled weight transposes + WAb + ew2 + Aw ======
__global__ __launch_bounds__(256) void k_prep(
    SrcPtrs S, float* __restrict__ pf,
    u16* __restrict__ WT, u16* __restrict__ w1T, u16* __restrict__ w2T,
    u16* __restrict__ WAb, u16* __restrict__ ew2, u16* __restrict__ Aw16,
    int* __restrict__ flagOut)
{
    __shared__ float tile[64][65];
    const unsigned* xw = (const unsigned*)S.p[0];
    int lane = threadIdx.x & 63;
    int cnt = 0;
    for (int i = lane; i < 512; i += 64) {
        float v = __uint_as_float((xw[i] & 0xFFFFu) << 16);
        if (!(fabsf(v) < 32.f)) cnt++;
    }
    bool isbf = wave_sum((float)cnt) < 16.f;
    if (blockIdx.x == 0 && threadIdx.x == 0) *flagOut = isbf ? 1 : 0;

    int blk = blockIdx.x, tid = threadIdx.x;
    if (blk < 131) {                               // small-param f32 convert
        int idx = blk * 256 + tid;
        if (idx < 33276) {
            int y = 17;
            #pragma unroll 1
            for (int t = 1; t < 18; t++) if (idx < NCV_OFF[t]) { y = t - 1; break; }
            pf[idx] = ldin(S.p[NCV_SRC[y]], idx - NCV_OFF[y], isbf);
        }
    } else if (blk < 211) {                        // tiled transposes: src[K][N] -> dst[N][K] bf16
        const void* src; u16* dst; int K, N, k0, n0;
        if (blk < 147) {                           // WT
            int t = blk - 131, l = t >> 2, tt = t & 3;
            src = (const char*)S.p[7] + (size_t)l * 16384 * (isbf ? 2 : 4);
            dst = WT + l * 16384; K = 128; N = 128; k0 = (tt >> 1) * 64; n0 = (tt & 1) * 64;
        } else if (blk < 179) {                    // w1T
            int t = blk - 147, l = t >> 3, tt = t & 7;
            src = (const char*)S.p[12] + (size_t)l * 32768 * (isbf ? 2 : 4);
            dst = w1T + l * 32768; K = 128; N = 256; k0 = (tt >> 2) * 64; n0 = (tt & 3) * 64;
        } else {                                   // w2T
            int t = blk - 179, l = t >> 3, tt = t & 7;
            src = (const char*)S.p[14] + (size_t)l * 32768 * (isbf ? 2 : 4);
            dst = w2T + l * 32768; K = 256; N = 128; k0 = (tt & 3) * 64; n0 = (tt >> 2) * 64;
        }
        int ty = tid >> 6, tx = tid & 63;
        #pragma unroll 4
        for (int i = 0; i < 16; i++) {
            int row = ty * 16 + i;
            tile[row][tx] = ldin(src, (k0 + row) * N + n0 + tx, isbf);
        }
        __syncthreads();
        #pragma unroll 4
        for (int i = 0; i < 16; i++) {
            int row = ty * 16 + i;
            dst[(n0 + row) * K + k0 + tx] = f2bf_bits(tile[tx][row]);
        }
    } else if (blk < 243) {                        // WAb[l][n16][k128] = (W @ [asrc|adst])^T
        int j = (blk - 211) * 256 + tid;
        int l = j >> 11, r = j & 2047, n = r >> 7, k = r & 127;
        int h = n & 7;
        const void* ap = (n < 8) ? S.p[8] : S.p[9];
        float sacc = 0.f;
        #pragma unroll 1
        for (int d = 0; d < 16; d++)
            sacc += ldin(S.p[7], l * 16384 + k * 128 + h * 16 + d, isbf)
                  * ldin(ap, l * 128 + h * 16 + d, isbf);
        WAb[j] = f2bf_bits(sacc);
    } else if (blk < 307) {                        // ew2 = log2e*(mask? ewa : -1e30)
        int j = (blk - 243) * 256 + tid;
        float sav = ldin(S.p[24], j, isbf);
        float ewv = ldin(S.p[27], j, isbf);
        ew2[j] = f2bf_bits(sav > 0.f ? ewv * LOG2E : -1e30f);
    } else {                                       // Aw row-normalized * 0.4, bf16
        __shared__ float red[2];
        int i = blk - 307, j = tid & 127;
        float v = 0.f;
        if (tid < 128) {
            float wmv = ldin(S.p[25], i * 128 + j, isbf);
            float wpv = ldin(S.p[26], i * 128 + j, isbf);
            v = wmv / (1.f + __expf(-wpv));
            float sm = wave_sum(v);
            if ((tid & 63) == 0) red[tid >> 6] = sm;
        }
        __syncthreads();
        if (tid < 128) {
            float tot = red[0] + red[1];
            Aw16[i * 128 + j] = f2bf_bits(0.4f * v / (tot + 1e-5f));
        }
    }
}

// ====== whole-network megakernel: 1 block/graph, 512 thr = 8 waves, 16 rows/wave ======
// R11 post-mortem: accS[] indexed by runtime loop vars (#pragma unroll 1) was demoted to
// SCRATCH since R3 -> 50-60 MB/dispatch HBM writes, the real per-layer wall. Fix: every
// accumulator-array index is now a compile-time constant (h-loop and pass-loop fully
// unrolled). Everything else identical to R11.
#define LDSB (128*STR*2*2 + 128*132*4 + 2560*4)
__global__ __launch_bounds__(512, 1) void k_net(
    const void* __restrict__ xraw, const int* __restrict__ flag,
    const float* __restrict__ pf,
    const u16* __restrict__ WTg, const u16* __restrict__ WAbg,
    const u16* __restrict__ Awg, const u16* __restrict__ ew2g,
    const u16* __restrict__ w1Tg, const u16* __restrict__ w2Tg,
    void* __restrict__ outv)
{
    extern __shared__ __align__(16) char smem[];
    u16* U1 = (u16*)smem;                      // [128][STR]
    u16* U2 = U1 + 128 * STR;                  // [128][STR]
    float* hres = (float*)(U2 + 128 * STR);    // [128][132]
    float* st2  = hres + 128 * 132;            // 2560 f32
    float* s2   = st2;                         // [8][128] f32
    u16*   t2u  = (u16*)(st2 + 1024);          // [8][128] bf16

    const int b = blockIdx.x;
    const int tid = threadIdx.x, lane = tid & 63, wv = tid >> 6;
    const int l15 = lane & 15, kg = lane >> 4;
    const int wrow = wv * 16;
    const int arow = wrow + l15;               // this lane's A-frag row
    const bool isbf = (*flag != 0);

    // ---------- embed: conv1d + BN + relu -> hres + U1(bf16) ----------
    {
        float xr[4][IND];
        #pragma unroll
        for (int r = 0; r < 4; r++) {
            int bn = b * NN + wrow + kg * 4 + r;
            #pragma unroll
            for (int k = 0; k < IND; k++) xr[r][k] = ldin(xraw, bn * IND + k, isbf);
        }
        #pragma unroll 1
        for (int nt = 0; nt < 8; nt++) {
            int d = nt * 16 + l15;
            float cwreg[IND];
            #pragma unroll
            for (int k = 0; k < IND; k++) cwreg[k] = pf[d * IND + k];
            float scale = rsqrtf(pf[1664 + d] + 1e-5f) * pf[1280 + d];
            float bias  = pf[1408 + d] - pf[1536 + d] * scale;
            float cbd   = pf[1152 + d];
            #pragma unroll
            for (int r = 0; r < 4; r++) {
                float a = cbd;
                #pragma unroll
                for (int k = 0; k < IND; k++) a = fmaf(xr[r][k], cwreg[k], a);
                a = fmaxf(fmaf(a, scale, bias), 0.f);
                int row = wrow + kg * 4 + r;
                hres[row * 132 + d] = a;
                U1[row * STR + d] = f2bf_bits(a);
            }
        }
    }

    // ---------- 4 layers ----------
    #pragma unroll 1
    for (int l = 0; l < LLY; l++) {
        const u16* WT  = WTg  + l * 16384;
        const u16* WAb = WAbg + l * 2048;
        const u16* w1T = w1Tg + l * 32768;
        const u16* w2T = w2Tg + l * 32768;
        const float* fb1 = pf + 2816 + l * 256;
        const float* fb2 = pf + 3840 + l * 128;
        const float* lng = pf + 1792 + l * 128;
        const float* lnb = pf + 2304 + l * 128;

        __syncthreads();                       // U2/s2/t2 free (prior cross-wave readers done)

        // ---- P1: hp = h @ W (own rows -> hpT); s,t = h @ (W·a) ----
        {
            CF acc[8], ast;
            #pragma unroll
            for (int r = 0; r < 4; r++) ast.f[r] = 0.f;
            #pragma unroll
            for (int nt = 0; nt < 8; nt++)
                #pragma unroll
                for (int r = 0; r < 4; r++) acc[nt].f[r] = 0.f;
            #pragma unroll
            for (int kk = 0; kk < 4; kk++) {
                bfrag af  = *(const bfrag*)&U1[arow * STR + kk*32 + kg*8];
                bfrag wab = *(const bfrag*)&WAb[l15 * 128 + kk*32 + kg*8];
                ast.v = MFMA(af, wab, ast.v);
                #pragma unroll
                for (int nt = 0; nt < 8; nt++) {
                    bfrag bw = *(const bfrag*)&WT[(nt*16 + l15) * 128 + kk*32 + kg*8];
                    acc[nt].v = MFMA(af, bw, acc[nt].v);
                }
            }
            #pragma unroll
            for (int nt = 0; nt < 8; nt++) {
                int col = nt*16 + l15;
                #pragma unroll
                for (int rp = 0; rp < 2; rp++) {
                    int row = wrow + kg*4 + rp*2;
                    *(unsigned*)&U2[col * STR + row] = pk2(acc[nt].f[rp*2], acc[nt].f[rp*2+1]);
                }
            }
            #pragma unroll
            for (int r = 0; r < 4; r++) {      // s (cols 0-7) f32, t (cols 8-15) bf16
                int node = wrow + kg*4 + r;
                float v = ast.f[r] * LOG2E;
                if (l15 < 8) s2[l15 * 128 + node] = v;
                else         t2u[(l15 - 8) * 128 + node] = f2bf_bits(v);
            }
        }
        __syncthreads();                       // hpT, s2, t2 ready

        // ---- P2: weak FIRST into accS (Aw pre-scaled 0.4) — all indices constant ----
        CF accS[8];
        #pragma unroll
        for (int nt = 0; nt < 8; nt++)
            #pragma unroll
            for (int r = 0; r < 4; r++) accS[nt].f[r] = 0.f;
        #pragma unroll
        for (int kk = 0; kk < 4; kk++) {
            bfrag awf = *(const bfrag*)&Awg[arow * 128 + kk*32 + kg*8];
            #pragma unroll
            for (int nt = 0; nt < 8; nt++) {
                bfrag hb2 = *(const bfrag*)&U2[(nt*16 + l15) * STR + kk*32 + kg*8];
                accS[nt].v = MFMA(awf, hb2, accS[nt].v);
            }
        }

        // ---- P3: attention, normalized P (×0.6/sm) into accS — h-loop FULLY unrolled ----
        BF e2f[4];
        #pragma unroll
        for (int kk = 0; kk < 4; kk++)
            e2f[kk].v = *(const bfrag*)&ew2g[arow * 128 + kk*32 + kg*8];
        #pragma unroll
        for (int h = 0; h < 8; h++) {
            bfrag hb[4];
            #pragma unroll
            for (int kk = 0; kk < 4; kk++)
                hb[kk] = *(const bfrag*)&U2[(h*16 + l15) * STR + kk*32 + kg*8];
            float sA = s2[h * 128 + arow];
            float pv[4][8];
            float sm = 0.f;
            #pragma unroll
            for (int kk = 0; kk < 4; kk++) {
                BF tb; tb.v = *(const bfrag*)&t2u[h * 128 + kk*32 + kg*8];
                #pragma unroll
                for (int j = 0; j < 8; j++) {
                    float x2 = sA + u2f(tb.u[j]);
                    float lk = fmaxf(x2, 0.2f * x2);                  // log2e*leaky
                    float p = __builtin_amdgcn_exp2f(lk + u2f(e2f[kk].u[j]));
                    pv[kk][j] = p; sm += p;
                }
            }
            sm += __shfl_xor(sm, 16, 64);
            sm += __shfl_xor(sm, 32, 64);
            float sc = 0.6f * __builtin_amdgcn_rcpf(sm);
            #pragma unroll
            for (int kk = 0; kk < 4; kk++) {
                BF pb;
                #pragma unroll
                for (int q = 0; q < 4; q++)
                    pb.w[q] = pk2(pv[kk][2*q] * sc, pv[kk][2*q+1] * sc);
                accS[h].v = MFMA(pb.v, hb[kk], accS[h].v);
            }
        }

        // ---- P4: g = relu(accS), LN -> U1 (own rows) ----
        #pragma unroll
        for (int r = 0; r < 4; r++) {
            float s1 = 0.f, sq = 0.f;
            #pragma unroll
            for (int nt = 0; nt < 8; nt++) {
                float x = fmaxf(accS[nt].f[r], 0.f);
                accS[nt].f[r] = x; s1 += x; sq = fmaf(x, x, sq);
            }
            #pragma unroll
            for (int m = 1; m <= 8; m <<= 1) { s1 += __shfl_xor(s1, m, 64); sq += __shfl_xor(sq, m, 64); }
            float mu = s1 * (1.f / 128.f);
            float var = sq * (1.f / 128.f) - mu * mu;
            float rs = rsqrtf(fmaxf(var, 0.f) + 1e-5f);
            #pragma unroll
            for (int nt = 0; nt < 8; nt++) {
                int col = nt*16 + l15;
                U1[(wrow + kg*4 + r) * STR + col] =
                    f2bf_bits(fmaf((accS[nt].f[r] - mu) * rs, lng[col], lnb[col]));
            }
        }

        __syncthreads();                       // all waves done with cross-wave hpT reads

        // ---- P5: FFN; hid in U2 (own rows); acc indices constant throughout ----
        CF acc2[8];
        #pragma unroll
        for (int nt = 0; nt < 8; nt++)
            #pragma unroll
            for (int r = 0; r < 4; r++) acc2[nt].f[r] = 0.f;
        #pragma unroll
        for (int nh = 0; nh < 2; nh++) {
            CF a1[8];
            #pragma unroll
            for (int nt = 0; nt < 8; nt++)
                #pragma unroll
                for (int r = 0; r < 4; r++) a1[nt].f[r] = 0.f;
            #pragma unroll
            for (int kk = 0; kk < 4; kk++) {
                bfrag gf = *(const bfrag*)&U1[arow * STR + kk*32 + kg*8];
                #pragma unroll
                for (int nt = 0; nt < 8; nt++) {
                    bfrag wf = *(const bfrag*)&w1T[(nh*128 + nt*16 + l15) * 128 + kk*32 + kg*8];
                    a1[nt].v = MFMA(gf, wf, a1[nt].v);
                }
            }
            #pragma unroll
            for (int nt = 0; nt < 8; nt++) {
                int col = nt*16 + l15;
                float b1v = fb1[nh*128 + col];
                #pragma unroll
                for (int r = 0; r < 4; r++)
                    U2[(wrow + kg*4 + r) * STR + col] = f2bf_bits(fmaxf(a1[nt].f[r] + b1v, 0.f));
            }
            #pragma unroll
            for (int kk = 0; kk < 4; kk++) {
                bfrag hf = *(const bfrag*)&U2[arow * STR + kk*32 + kg*8];
                #pragma unroll
                for (int nt = 0; nt < 8; nt++) {
                    bfrag wf = *(const bfrag*)&w2T[(nt*16 + l15) * 256 + nh*128 + kk*32 + kg*8];
                    acc2[nt].v = MFMA(hf, wf, acc2[nt].v);
                }
            }
        }

        // ---- epilogue: hres += ffn + b2; rebuild U1 h16 for next layer ----
        #pragma unroll
        for (int nt = 0; nt < 8; nt++) {
            int col = nt*16 + l15;
            float b2v = fb2[col];
            #pragma unroll
            for (int r = 0; r < 4; r++) {
                int row = wrow + kg*4 + r;
                float hv = hres[row * 132 + col] + acc2[nt].f[r] + b2v;
                hres[row * 132 + col] = hv;
                if (l < LLY - 1) U1[row * STR + col] = f2bf_bits(hv);
            }
        }
    }

    // ---------- final LN + node-sum (proj commutes with mean) + head ----------
    const float* ng = pf + 4352;
    const float* nb = pf + 4480;
    float pacc[8];
    #pragma unroll
    for (int nt = 0; nt < 8; nt++) pacc[nt] = 0.f;
    #pragma unroll
    for (int r = 0; r < 4; r++) {
        int row = wrow + kg*4 + r;
        float hvv[8];
        float s1 = 0.f, sq = 0.f;
        #pragma unroll
        for (int nt = 0; nt < 8; nt++) {
            float x = hres[row * 132 + nt*16 + l15];
            hvv[nt] = x; s1 += x; sq = fmaf(x, x, sq);
        }
        #pragma unroll
        for (int m = 1; m <= 8; m <<= 1) { s1 += __shfl_xor(s1, m, 64); sq += __shfl_xor(sq, m, 64); }
        float mu = s1 * (1.f / 128.f);
        float var = sq * (1.f / 128.f) - mu * mu;
        float rs = rsqrtf(fmaxf(var, 0.f) + 1e-5f);
        #pragma unroll
        for (int nt = 0; nt < 8; nt++)
            pacc[nt] += fmaf((hvv[nt] - mu) * rs, ng[nt*16 + l15], nb[nt*16 + l15]);
    }
    #pragma unroll
    for (int nt = 0; nt < 8; nt++) {
        pacc[nt] += __shfl_xor(pacc[nt], 16, 64);
        pacc[nt] += __shfl_xor(pacc[nt], 32, 64);
    }
    __syncthreads();                           // st2 dead -> reuse
    if (kg == 0) {
        #pragma unroll
        for (int nt = 0; nt < 8; nt++) st2[wv * 128 + nt*16 + l15] = pacc[nt];
    }
    __syncthreads();
    if (tid < 128) {                           // pooled mean
        float tot = 0.f;
        #pragma unroll
        for (int w = 0; w < 8; w++) tot += st2[w * 128 + tid];
        st2[1024 + tid] = tot * (1.f / 128.f);
    }
    __syncthreads();
    {                                          // proj, 4 k-quarters
        int e = tid & 127, kq = tid >> 7;
        float a = 0.f;
        #pragma unroll 4
        for (int k = kq * 32; k < kq * 32 + 32; k++)
            a = fmaf(st2[1024 + k], pf[4608 + k * 128 + e], a);
        st2[1152 + kq * 128 + e] = a;
    }
    __syncthreads();
    if (tid < 128)
        st2[1664 + tid] = st2[1152 + tid] + st2[1280 + tid] + st2[1408 + tid] + st2[1536 + tid]
                        + pf[20992 + tid];
    __syncthreads();
    if (tid < 64) {
        float a1 = pf[29312 + tid];
        #pragma unroll 4
        for (int k = 0; k < 128; k++) a1 = fmaf(st2[1664 + k], pf[21120 + k * 64 + tid], a1);
        st2[1792 + tid] = fmaxf(a1, 0.f);
    }
    __syncthreads();
    if (tid < OUTD) {
        float a2 = pf[33216 + tid];
        #pragma unroll 4
        for (int k = 0; k < 64; k++) a2 = fmaf(st2[1792 + k], pf[29376 + k * OUTD + tid], a2);
        if (isbf) ((bf16*)outv)[b * OUTD + tid] = __float2bfloat16(a2);
        else      ((float*)outv)[b * OUTD + tid] = a2;
    }
}

extern "C" void kernel_launch(void* const* d_in, const int* in_sizes, int n_in,
                              void* d_out, int out_size, void* d_ws, size_t ws_size,
                              hipStream_t stream)
{
    float* ws = (float*)d_ws;
    float* pf = ws;                                // compact f32 params [0..33276)
    int*   flag = (int*)(ws + 33280);
    u16* WT16   = (u16*)(ws + 33536);              // 65,536
    u16* w1T16  = WT16 + 65536;                    // 131,072
    u16* w2T16  = w1T16 + 131072;                  // 131,072
    u16* WAb16  = w2T16 + 131072;                  // 8,192
    u16* Aw16   = WAb16 + 8192;                    // 16,384
    u16* ew2p   = Aw16 + 16384;                    // 16,384

    SrcPtrs S;
    for (int i = 0; i < 28; i++) S.p[i] = d_in[i];

    hipFuncSetAttribute((const void*)k_net,
                        hipFuncAttributeMaxDynamicSharedMemorySize, LDSB);

    k_prep<<<435, 256, 0, stream>>>(S, pf, WT16, w1T16, w2T16, WAb16, ew2p, Aw16, flag);
    k_net<<<BB, 512, LDSB, stream>>>(d_in[0], flag, pf,
                                     WT16, WAb16, Aw16, ew2p, w1T16, w2T16, d_out);
}